// Round 4
// baseline (420.308 us; speedup 1.0000x reference)
//
#include <hip/hip_runtime.h>

// FastfoodProjection: out = H * diag(G) * P * H * diag(B/8192) * pad(x), rows of
// 8192 (x rows 4096 zero-padded). H = unnormalized Hadamard_8192; the two
// 1/sqrt(8192) factors are folded into B at load.
//
// Single-wave design: 64-thread workgroups, one row per block, 128 elements
// per lane in registers. j (13 bits) maps to layouts:
//   L0 (load/store):  j = m*256 + l*4 + e   e=j[0:2], l=j[2:8], m=j[8:13]
//   L1 (exchange):    j = l*128 + m*4 + e   e=j[0:2], m=j[2:7], l=j[7:13]
// Register index r = m*4+e. FWHT = p1 (all 7 reg bits, in L0: j{0,1,8..12})
// -> one LDS exchange -> p2 (reg bits 2..6, in L1: j{2..6}) + DPP butterfly
// for j bit 7 (= lane bit 0, quad_perm swap). FWHT2 mirrors it backwards
// (gather lands in L1, p1' covers j{0..6}, +DPP, exchange, p2' covers
// j{8..12} in L0) so stores are fully coalesced.
// => 3 LDS roundtrips total (E1, final-write+gather, E2), all b128 except the
// random gather; +4 words per 128 padding makes every exchange conflict-free.
// Single wave per block: __syncthreads lowers to a wave-internal waitcnt
// (no s_barrier), and same-wave DS ordering covers the WAR hazards.
//
// NOTE: nontemporal builtins require native clang vector types, not HIP's
// HIP_vector_type — hence f4/i4 ext_vector_type below (round-3 compile fix).

constexpr int NT = 64;
constexpr int LDS_WORDS = 8192 + 256;  // +4 words per 128 -> 33 KB, 4 blocks/CU

using f4 = __attribute__((ext_vector_type(4))) float;
using i4 = __attribute__((ext_vector_type(4))) int;

__device__ __forceinline__ int padw(int w) { return w + ((w >> 7) << 2); }

template <int FIRST>
__device__ __forceinline__ void bfly(float (&v)[128]) {
    #pragma unroll
    for (int b = FIRST; b < 128; b <<= 1) {
        #pragma unroll
        for (int r = 0; r < 128; ++r) {
            if ((r & b) == 0) {
                float a = v[r], c = v[r ^ b];
                v[r]     = a + c;
                v[r ^ b] = a - c;
            }
        }
    }
}

// Butterfly across lane^1 (j bit 7 in layout L1): quad_perm(1,0,3,2) DPP.
// even lane: a+b ; odd lane: a-b  ==> v = v*sgn + partner.
__device__ __forceinline__ void bfly_lane1(float (&v)[128], float sgn) {
    #pragma unroll
    for (int r = 0; r < 128; ++r) {
        int t = __builtin_amdgcn_update_dpp(0, __float_as_int(v[r]),
                                            0xB1 /*quad_perm(1,0,3,2)*/,
                                            0xF, 0xF, true);
        v[r] = fmaf(v[r], sgn, __int_as_float(t));
    }
}

__global__ __launch_bounds__(NT, 1) void fastfood_kernel(
    const float* __restrict__ x, const float* __restrict__ Bv,
    const float* __restrict__ Gv, const int* __restrict__ perm,
    float* __restrict__ out)
{
    __shared__ float lds[LDS_WORDS];
    const int l = threadIdx.x;
    const int row = blockIdx.x;
    const float* xrow = x + (size_t)row * 4096;
    float v[128];

    const float scale = 1.0f / 8192.0f;

    // ---- load + (B*scale) multiply, layout L0; x covers j<4096 <=> m<16
    #pragma unroll
    for (int m = 0; m < 16; ++m) {
        f4 xv = __builtin_nontemporal_load((const f4*)(xrow + m * 256 + 4 * l));
        f4 bv = *(const f4*)(Bv + m * 256 + 4 * l);
        v[4 * m + 0] = xv.x * (bv.x * scale);
        v[4 * m + 1] = xv.y * (bv.y * scale);
        v[4 * m + 2] = xv.z * (bv.z * scale);
        v[4 * m + 3] = xv.w * (bv.w * scale);
    }
    #pragma unroll
    for (int r = 64; r < 128; ++r) v[r] = 0.0f;

    // ---- FWHT1 p1: j bits {0,1,8..12} == all 7 register bits
    bfly<1>(v);

    // ---- E1: write L0, read L1 (both b128, conflict-free with padding)
    const int wL0 = 4 * l + 4 * (l >> 5);  // + m*264
    const int wL1 = 132 * l;               // + m*4
    #pragma unroll
    for (int m = 0; m < 32; ++m)
        *(f4*)&lds[m * 264 + wL0] = f4{v[4 * m], v[4 * m + 1], v[4 * m + 2], v[4 * m + 3]};
    __syncthreads();
    #pragma unroll
    for (int m = 0; m < 32; ++m) {
        f4 d = *(const f4*)&lds[wL1 + 4 * m];
        v[4 * m] = d.x; v[4 * m + 1] = d.y; v[4 * m + 2] = d.z; v[4 * m + 3] = d.w;
    }

    // ---- FWHT1 p2: j bits {2..6} (reg bits 2..6), then j bit 7 via DPP
    bfly<4>(v);
    const float sgn = (l & 1) ? -1.0f : 1.0f;
    bfly_lane1(v, sgn);

    // ---- write FWHT1 result y (L1 addresses; same words this lane read)
    #pragma unroll
    for (int m = 0; m < 32; ++m)
        *(f4*)&lds[wL1 + 4 * m] = f4{v[4 * m], v[4 * m + 1], v[4 * m + 2], v[4 * m + 3]};
    __syncthreads();

    // ---- gather z[j] = y[perm[j]] * G[j], j in L1 layout (lane l owns one
    //      contiguous 512B j-segment; perm/G reads are L2-hot, 32 KB each)
    const int jbase = 128 * l;
    #pragma unroll
    for (int m = 0; m < 32; ++m) {
        i4 q = *(const i4*)(perm + jbase + 4 * m);
        f4 g = *(const f4*)(Gv + jbase + 4 * m);
        v[4 * m + 0] = lds[padw(q.x)] * g.x;
        v[4 * m + 1] = lds[padw(q.y)] * g.y;
        v[4 * m + 2] = lds[padw(q.z)] * g.z;
        v[4 * m + 3] = lds[padw(q.w)] * g.w;
    }

    // ---- FWHT2 p1': j bits {0..6} == all reg bits, then j bit 7 via DPP
    bfly<1>(v);
    bfly_lane1(v, sgn);

    // ---- E2: write L1, read L0
    #pragma unroll
    for (int m = 0; m < 32; ++m)
        *(f4*)&lds[wL1 + 4 * m] = f4{v[4 * m], v[4 * m + 1], v[4 * m + 2], v[4 * m + 3]};
    __syncthreads();
    #pragma unroll
    for (int m = 0; m < 32; ++m) {
        f4 d = *(const f4*)&lds[m * 264 + wL0];
        v[4 * m] = d.x; v[4 * m + 1] = d.y; v[4 * m + 2] = d.z; v[4 * m + 3] = d.w;
    }

    // ---- FWHT2 p2': j bits {8..12} (reg bits 2..6 in L0)
    bfly<4>(v);

    // ---- store, fully coalesced (1 KB per wave instruction), nontemporal
    float* orow = out + (size_t)row * 8192;
    #pragma unroll
    for (int m = 0; m < 32; ++m)
        __builtin_nontemporal_store(
            f4{v[4 * m], v[4 * m + 1], v[4 * m + 2], v[4 * m + 3]},
            (f4*)(orow + m * 256 + 4 * l));
}

extern "C" void kernel_launch(void* const* d_in, const int* in_sizes, int n_in,
                              void* d_out, int out_size, void* d_ws, size_t ws_size,
                              hipStream_t stream) {
    const float* x    = (const float*)d_in[0];
    const float* Bv   = (const float*)d_in[1];
    const float* Gv   = (const float*)d_in[2];
    const int*   perm = (const int*)d_in[3];
    float* out = (float*)d_out;
    fastfood_kernel<<<dim3(8192), dim3(NT), 0, stream>>>(x, Bv, Gv, perm, out);
}